// Round 11
// baseline (610.031 us; speedup 1.0000x reference)
//
#include <hip/hip_runtime.h>
#include <hip/hip_bf16.h>

#define B_   4
#define NPTS 32768
#define BN   131072
#define RES  64
#define R2   4096
#define DIM  128
#define K2   256
#define NBLK 5
#define NSEG (3*B_*R2)        // 49152 segments (plane,batch,cell)

typedef __bf16 bf16x8 __attribute__((ext_vector_type(8)));
typedef float  f32x16 __attribute__((ext_vector_type(16)));
typedef unsigned int uintv4 __attribute__((ext_vector_type(4)));

#define MFMA(a,b,c) __builtin_amdgcn_mfma_f32_32x32x16_bf16((a),(b),(c),0,0,0)

// ---------------- workspace layout (bytes) ----------------
#define O_IDX  0                          // BN*16 (int4 per point)
#define O_CNT  (O_IDX + BN*16)            // NSEG*4
#define O_OFF  (O_CNT + NSEG*4)
#define O_WOFF (O_OFF + NSEG*4)
#define O_LIST (O_WOFF + NSEG*4)          // 3*BN*4
#define O_H    (O_LIST + 3*BN*4)          // BN*DIM*2
#define O_GRID (O_H + BN*DIM*2)           // NSEG*DIM*2 (bf16 max-grid; reused as mean-grid)
#define O_W    (O_GRID + NSEG*DIM*2)      // fragment-ordered bf16 weights
#define WBLK_ELEMS 81920                  // w0f(32768)+wsf(32768)+w1f(16384)

// ---------------- output layout (floats) ----------------
#define OUT_C_OFF   393216
#define OUT_TRI_OFF 17170432

// ---------------- helpers ----------------
__device__ __forceinline__ unsigned short f2bf(float f){
  unsigned int u = __float_as_uint(f);
  return (unsigned short)((u + 0x7fffu + ((u >> 16) & 1u)) >> 16);
}
__device__ __forceinline__ float bflo(unsigned int u){ return __uint_as_float(u << 16); }
__device__ __forceinline__ float bfhi(unsigned int u){ return __uint_as_float(u & 0xffff0000u); }
__device__ __forceinline__ int coord_bin(float u){
  float p = u / 1.101f + 0.5f;                 // matches f32(1.0+PAD+0.001)
  p = fminf(fmaxf(p, 0.0f), (float)(1.0 - 1e-6));
  int i = (int)(p * 64.0f);
  return i < 0 ? 0 : (i > 63 ? 63 : i);
}
__device__ __forceinline__ unsigned int pk_relu(unsigned int a){
  unsigned int r, z = 0;
  asm("v_pk_max_f16 %0, %1, %2" : "=v"(r) : "v"(a), "v"(z));
  return r;
}
__device__ __forceinline__ bf16x8 relu8(bf16x8 v){
  uintv4 u = __builtin_bit_cast(uintv4, v);
  u[0] = pk_relu(u[0]); u[1] = pk_relu(u[1]); u[2] = pk_relu(u[2]); u[3] = pk_relu(u[3]);
  return __builtin_bit_cast(bf16x8, u);
}

// ---------------- prep: indices (int4-packed), counts, xyz copy ----------------
__global__ void k_prep(const float* __restrict__ x, float* __restrict__ out_xyz,
                       int* __restrict__ idx4, int* __restrict__ cnt){
  int p = blockIdx.x * 256 + threadIdx.x;
  if (p >= BN) return;
  float x0 = x[p*3+0], x1 = x[p*3+1], x2 = x[p*3+2];
  out_xyz[p*3+0] = x0; out_xyz[p*3+1] = x1; out_xyz[p*3+2] = x2;
  int b = p >> 15;
  int c0 = coord_bin(x0) + 64*coord_bin(x2);   // plane (0,2)
  int c1 = coord_bin(x0) + 64*coord_bin(x1);   // plane (0,1)
  int c2 = coord_bin(x1) + 64*coord_bin(x2);   // plane (1,2)
  int4 c4; c4.x = c0; c4.y = c1; c4.z = c2; c4.w = 0;
  *(int4*)(idx4 + p*4) = c4;
  atomicAdd(&cnt[(0*B_+b)*R2 + c0], 1);
  atomicAdd(&cnt[(1*B_+b)*R2 + c1], 1);
  atomicAdd(&cnt[(2*B_+b)*R2 + c2], 1);
}

// ---------------- exclusive scan over NSEG counts ----------------
__global__ __launch_bounds__(1024) void k_scan(const int* __restrict__ cnt,
                                               int* __restrict__ off, int* __restrict__ woff){
  __shared__ int part[1024];
  const int t = threadIdx.x;
  const int PER = NSEG / 1024;     // 48
  const int base = t * PER;
  int s = 0;
  for (int i = 0; i < PER; ++i) s += cnt[base+i];
  part[t] = s;
  __syncthreads();
  for (int d = 1; d < 1024; d <<= 1){
    int v = (t >= d) ? part[t-d] : 0;
    __syncthreads();
    part[t] += v;
    __syncthreads();
  }
  int acc = (t == 0) ? 0 : part[t-1];
  for (int i = 0; i < PER; ++i){
    int c = cnt[base+i];
    off[base+i] = acc; woff[base+i] = acc;
    acc += c;
  }
}

// ---------------- bin points into per-cell lists ----------------
__global__ void k_bin(const int* __restrict__ idx4, int* __restrict__ woff, int* __restrict__ list){
  int p = blockIdx.x * 256 + threadIdx.x;
  if (p >= BN) return;
  int b = p >> 15;
  int4 c4 = *(const int4*)(idx4 + p*4);
  int cs[3] = {c4.x, c4.y, c4.z};
  #pragma unroll
  for (int pl = 0; pl < 3; ++pl){
    int s = (pl*B_+b)*R2 + cs[pl];
    int slot = atomicAdd(&woff[s], 1);
    list[slot] = p;
  }
}

// ---------------- prep: weights -> bf16, FRAGMENT ORDER ----------------
__global__ void k_prepw(const float* __restrict__ fc0, const float* __restrict__ fc1,
                        const float* __restrict__ scw, const float* __restrict__ fcc,
                        unsigned short* __restrict__ wdst){
  int t = blockIdx.x * 256 + threadIdx.x;
  if (t < 163840){                          // w0f per block: [4][16][64][8]  (K=256)
    int b = t >> 15, r = t & 32767;
    int j = r & 7, l = (r >> 3) & 63, ks = (r >> 9) & 15, w = r >> 13;
    int n = w*32 + (l & 31);
    int k = ks*16 + (l >> 5)*8 + j;
    wdst[b*WBLK_ELEMS + r] = f2bf(fc0[(b*256 + k)*128 + n]);
  } else if (t < 327680){                   // wsf per block
    int t2 = t - 163840;
    int b = t2 >> 15, r = t2 & 32767;
    int j = r & 7, l = (r >> 3) & 63, ks = (r >> 9) & 15, w = r >> 13;
    int n = w*32 + (l & 31);
    int k = ks*16 + (l >> 5)*8 + j;
    wdst[b*WBLK_ELEMS + 32768 + r] = f2bf(scw[(b*256 + k)*128 + n]);
  } else if (t < 409600){                   // w1f per block: [4][8][64][8]  (K=128)
    int t2 = t - 327680;
    int b = t2 >> 14, r = t2 & 16383;
    int j = r & 7, l = (r >> 3) & 63, ks = (r >> 9) & 7, w = (r >> 12) & 3;
    int n = w*32 + (l & 31);
    int k = ks*16 + (l >> 5)*8 + j;
    wdst[b*WBLK_ELEMS + 65536 + r] = f2bf(fc1[(b*128 + k)*128 + n]);
  } else if (t < 425984){                   // fcf: [4][8][64][8]
    int r = t - 409600;
    int j = r & 7, l = (r >> 3) & 63, ks = (r >> 9) & 7, w = (r >> 12) & 3;
    int n = w*32 + (l & 31);
    int k = ks*16 + (l >> 5)*8 + j;
    wdst[5*WBLK_ELEMS + r] = f2bf(fcc[k*128 + n]);
  }
}

// ---------------- per-cell max (gather-reduce, no atomics) ----------------
__global__ __launch_bounds__(256) void k_cellmax(const unsigned short* __restrict__ h,
    const int* __restrict__ off, const int* __restrict__ cnt,
    const int* __restrict__ list, unsigned short* __restrict__ gbf){
  const int seg = (blockIdx.x * 256 + threadIdx.x) >> 6;   // 49152 waves
  const int l = threadIdx.x & 63;
  const int base = off[seg], n = cnt[seg];
  float m0 = -INFINITY, m1 = -INFINITY;
  int i = 0;
  for (; i + 4 <= n; i += 4){
    int p0 = list[base+i], p1 = list[base+i+1], p2 = list[base+i+2], p3 = list[base+i+3];
    unsigned int u0 = *(const unsigned int*)(h + p0*DIM + 2*l);
    unsigned int u1 = *(const unsigned int*)(h + p1*DIM + 2*l);
    unsigned int u2 = *(const unsigned int*)(h + p2*DIM + 2*l);
    unsigned int u3 = *(const unsigned int*)(h + p3*DIM + 2*l);
    m0 = fmaxf(fmaxf(fmaxf(m0, bflo(u0)), fmaxf(bflo(u1), bflo(u2))), bflo(u3));
    m1 = fmaxf(fmaxf(fmaxf(m1, bfhi(u0)), fmaxf(bfhi(u1), bfhi(u2))), bfhi(u3));
  }
  for (; i < n; ++i){
    int p = list[base+i];
    unsigned int u = *(const unsigned int*)(h + p*DIM + 2*l);
    m0 = fmaxf(m0, bflo(u)); m1 = fmaxf(m1, bfhi(u));
  }
  unsigned int o = 0;
  if (n > 0) o = (__float_as_uint(m0) >> 16) | (__float_as_uint(m1) & 0xffff0000u);
  *(unsigned int*)(gbf + (size_t)seg*DIM + 2*l) = o;
}

// ---------------- fused residual block (64-pt tile, 32 KB LDS, 4-bit swizzle) ----------------
// MODE 0: stem input. MODE 1: concat(h,pool). MODE 2: MODE1 + fused c = h@fc + b.
template<int MODE>
__global__ __launch_bounds__(256, 4) void k_block(
    const float* __restrict__ x,
    const float* __restrict__ stem_w, const float* __restrict__ stem_b,
    unsigned short* __restrict__ h,
    const unsigned short* __restrict__ gbf, const int* __restrict__ idx4,
    const unsigned short* __restrict__ wT,
    const float* __restrict__ b0g, const float* __restrict__ b1g, const float* __restrict__ bsg,
    const unsigned short* __restrict__ fcf, const float* __restrict__ fcb,
    float* __restrict__ cout)
{
  __shared__ unsigned short lh2[64*256];   // 32768 B
  const int t = threadIdx.x;
  const int tile0 = blockIdx.x * 64;

  if (MODE == 0){
    const int dg8 = (t & 31) * 8;
    const int prow = t >> 5;
    float wa[8], wb[8], wc[8], bb[8];
    #pragma unroll
    for (int j = 0; j < 8; ++j){
      wa[j] = stem_w[dg8+j]; wb[j] = stem_w[256+dg8+j]; wc[j] = stem_w[512+dg8+j];
      bb[j] = stem_b[dg8+j];
    }
    #pragma unroll
    for (int pass = 0; pass < 8; ++pass){
      int p = prow + pass*8;
      int pg = tile0 + p;
      float x0 = x[pg*3+0], x1 = x[pg*3+1], x2 = x[pg*3+2];
      unsigned int pk[4];
      #pragma unroll
      for (int j = 0; j < 4; ++j){
        float v0 = bb[2*j]   + x0*wa[2*j]   + x1*wb[2*j]   + x2*wc[2*j];
        float v1 = bb[2*j+1] + x0*wa[2*j+1] + x1*wb[2*j+1] + x2*wc[2*j+1];
        pk[j] = (unsigned int)f2bf(v0) | ((unsigned int)f2bf(v1) << 16);
      }
      uint4 q; q.x = pk[0]; q.y = pk[1]; q.z = pk[2]; q.w = pk[3];
      *(uint4*)((char*)lh2 + p*512 + ((dg8*2) ^ ((p & 15) << 4))) = q;
    }
  } else {
    const int dg4 = (t & 31) * 4;
    const int prow = t >> 5;
    // phase 1: preload all cell indices (fully unrolled -> registers)
    int4 cl[8];
    #pragma unroll
    for (int pass = 0; pass < 8; ++pass)
      cl[pass] = *(const int4*)(idx4 + (tile0 + prow + pass*8)*4);
    // phase 2: gather + stage (fully unrolled so cl[pass] is static)
    #pragma unroll
    for (int pass = 0; pass < 8; ++pass){
      int p = prow + pass*8;
      int pg = tile0 + p;
      int b = pg >> 15;
      uint2 hv = *(const uint2*)(h + pg*DIM + dg4);
      const unsigned short* g0 = gbf + ((size_t)((0*B_+b)*R2 + cl[pass].x))*DIM + dg4;
      const unsigned short* g1 = gbf + ((size_t)((1*B_+b)*R2 + cl[pass].y))*DIM + dg4;
      const unsigned short* g2 = gbf + ((size_t)((2*B_+b)*R2 + cl[pass].z))*DIM + dg4;
      uint2 v0 = *(const uint2*)g0;
      uint2 v1 = *(const uint2*)g1;
      uint2 v2 = *(const uint2*)g2;
      *(uint2*)((char*)lh2 + p*512 + ((dg4*2) ^ ((p & 15) << 4))) = hv;
      float s0 = bflo(v0.x) + bflo(v1.x) + bflo(v2.x);
      float s1 = bfhi(v0.x) + bfhi(v1.x) + bfhi(v2.x);
      float s2 = bflo(v0.y) + bflo(v1.y) + bflo(v2.y);
      float s3 = bfhi(v0.y) + bfhi(v1.y) + bfhi(v2.y);
      uint2 pv;
      pv.x = (unsigned int)f2bf(s0) | ((unsigned int)f2bf(s1) << 16);
      pv.y = (unsigned int)f2bf(s2) | ((unsigned int)f2bf(s3) << 16);
      *(uint2*)((char*)lh2 + p*512 + (((128 + dg4)*2) ^ ((p & 15) << 4))) = pv;
    }
  }
  __syncthreads();

  // ---- GEMM phase: A = weights (fragment-ordered), B = points (LDS) ----
  const int w  = t >> 6;
  const int l  = t & 63;
  const int lm = l & 31;
  const int hi = l >> 5;
  const int D0 = w * 32;
  const int swz  = (lm & 15) << 4;
  const unsigned short* w0f = wT +          ((size_t)w*16*64 + l)*8;
  const unsigned short* wsf = wT + 32768 +  ((size_t)w*16*64 + l)*8;
  const unsigned short* w1f = wT + 65536 +  ((size_t)w* 8*64 + l)*8;

  f32x16 an0, an1, as0, as1;
  #pragma unroll
  for (int i = 0; i < 16; ++i){ an0[i] = 0.f; an1[i] = 0.f; as0[i] = 0.f; as1[i] = 0.f; }

  const char* lr0 = (const char*)lh2 + lm*512;
  const char* lr1 = (const char*)lh2 + (32+lm)*512;

  #pragma unroll
  for (int ks = 0; ks < 16; ++ks){
    bf16x8 a0 = *(const bf16x8*)(w0f + ks*512);
    bf16x8 a1 = *(const bf16x8*)(wsf + ks*512);
    int kb = (ks*32 + hi*16) ^ swz;
    bf16x8 br0 = *(const bf16x8*)(lr0 + kb);
    bf16x8 br1 = *(const bf16x8*)(lr1 + kb);
    an0 = MFMA(a0, relu8(br0), an0);
    as0 = MFMA(a1, br0, as0);
    an1 = MFMA(a0, relu8(br1), an1);
    as1 = MFMA(a1, br1, as1);
  }

  __syncthreads();   // all waves done reading lh2 before aliased net-write

  // net = GEMM1 + b0, relu, write bf16 to lnet (= first 16 KB of lh2)
  {
    char* nr0 = (char*)lh2 + lm*256;
    char* nr1 = (char*)lh2 + (32+lm)*256;
    #pragma unroll
    for (int g = 0; g < 4; ++g){
      int d0 = D0 + 8*g + 4*hi;
      float q0 = b0g[d0], q1 = b0g[d0+1], q2 = b0g[d0+2], q3 = b0g[d0+3];
      uint2 u0, u1;
      {
        float v0 = fmaxf(an0[4*g+0]+q0, 0.f), v1 = fmaxf(an0[4*g+1]+q1, 0.f);
        float v2 = fmaxf(an0[4*g+2]+q2, 0.f), v3 = fmaxf(an0[4*g+3]+q3, 0.f);
        u0.x = (unsigned int)f2bf(v0) | ((unsigned int)f2bf(v1) << 16);
        u0.y = (unsigned int)f2bf(v2) | ((unsigned int)f2bf(v3) << 16);
      }
      {
        float v0 = fmaxf(an1[4*g+0]+q0, 0.f), v1 = fmaxf(an1[4*g+1]+q1, 0.f);
        float v2 = fmaxf(an1[4*g+2]+q2, 0.f), v3 = fmaxf(an1[4*g+3]+q3, 0.f);
        u1.x = (unsigned int)f2bf(v0) | ((unsigned int)f2bf(v1) << 16);
        u1.y = (unsigned int)f2bf(v2) | ((unsigned int)f2bf(v3) << 16);
      }
      int ob = (d0*2) ^ swz;
      *(uint2*)(nr0 + ob) = u0;
      *(uint2*)(nr1 + ob) = u1;
    }
  }
  __syncthreads();

  // dx = relu(net) @ w1
  f32x16 ad0, ad1;
  #pragma unroll
  for (int i = 0; i < 16; ++i){ ad0[i] = 0.f; ad1[i] = 0.f; }
  const char* nr0c = (const char*)lh2 + lm*256;
  const char* nr1c = (const char*)lh2 + (32+lm)*256;
  #pragma unroll
  for (int ks = 0; ks < 8; ++ks){
    bf16x8 a = *(const bf16x8*)(w1f + ks*512);
    int kb = (ks*32 + hi*16) ^ swz;
    ad0 = MFMA(a, *(const bf16x8*)(nr0c + kb), ad0);
    ad1 = MFMA(a, *(const bf16x8*)(nr1c + kb), ad1);
  }

  // h_next = sc + bs + dx + b1 ; keep packed values for MODE2 fusion
  uint2 oa[4], ob_[4];
  #pragma unroll
  for (int g = 0; g < 4; ++g){
    int d0 = D0 + 8*g + 4*hi;
    float p0 = b1g[d0]   + bsg[d0];
    float p1 = b1g[d0+1] + bsg[d0+1];
    float p2 = b1g[d0+2] + bsg[d0+2];
    float p3 = b1g[d0+3] + bsg[d0+3];
    {
      float v0 = as0[4*g+0]+ad0[4*g+0]+p0, v1 = as0[4*g+1]+ad0[4*g+1]+p1;
      float v2 = as0[4*g+2]+ad0[4*g+2]+p2, v3 = as0[4*g+3]+ad0[4*g+3]+p3;
      oa[g].x = (unsigned int)f2bf(v0) | ((unsigned int)f2bf(v1) << 16);
      oa[g].y = (unsigned int)f2bf(v2) | ((unsigned int)f2bf(v3) << 16);
      *(uint2*)(h + (tile0 + lm)*DIM + d0) = oa[g];
    }
    {
      float v0 = as1[4*g+0]+ad1[4*g+0]+p0, v1 = as1[4*g+1]+ad1[4*g+1]+p1;
      float v2 = as1[4*g+2]+ad1[4*g+2]+p2, v3 = as1[4*g+3]+ad1[4*g+3]+p3;
      ob_[g].x = (unsigned int)f2bf(v0) | ((unsigned int)f2bf(v1) << 16);
      ob_[g].y = (unsigned int)f2bf(v2) | ((unsigned int)f2bf(v3) << 16);
      *(uint2*)(h + (tile0 + 32 + lm)*DIM + d0) = ob_[g];
    }
  }

  if (MODE == 2){
    // ---- fused final projection: c = h@fc + b, h-tile staged via lh2 ----
    __syncthreads();   // all waves done reading lnet before overwrite
    {
      char* hr0 = (char*)lh2 + lm*256;
      char* hr1 = (char*)lh2 + (32+lm)*256;
      #pragma unroll
      for (int g = 0; g < 4; ++g){
        int d0 = D0 + 8*g + 4*hi;
        int ob = (d0*2) ^ swz;
        *(uint2*)(hr0 + ob) = oa[g];
        *(uint2*)(hr1 + ob) = ob_[g];
      }
    }
    __syncthreads();
    const unsigned short* fw = fcf + ((size_t)w*8*64 + l)*8;
    f32x16 ac0, ac1;
    #pragma unroll
    for (int i = 0; i < 16; ++i){ ac0[i] = 0.f; ac1[i] = 0.f; }
    #pragma unroll
    for (int ks = 0; ks < 8; ++ks){
      bf16x8 a = *(const bf16x8*)(fw + ks*512);
      int kb = (ks*32 + hi*16) ^ swz;
      ac0 = MFMA(a, *(const bf16x8*)(nr0c + kb), ac0);
      ac1 = MFMA(a, *(const bf16x8*)(nr1c + kb), ac1);
    }
    #pragma unroll
    for (int g = 0; g < 4; ++g){
      int d0 = D0 + 8*g + 4*hi;
      float q0 = fcb[d0], q1 = fcb[d0+1], q2 = fcb[d0+2], q3 = fcb[d0+3];
      {
        int pg = tile0 + lm;
        float4 f4;
        f4.x = ac0[4*g+0]+q0; f4.y = ac0[4*g+1]+q1; f4.z = ac0[4*g+2]+q2; f4.w = ac0[4*g+3]+q3;
        *(float4*)(cout + (size_t)pg*DIM + d0) = f4;
      }
      {
        int pg = tile0 + 32 + lm;
        float4 f4;
        f4.x = ac1[4*g+0]+q0; f4.y = ac1[4*g+1]+q1; f4.z = ac1[4*g+2]+q2; f4.w = ac1[4*g+3]+q3;
        *(float4*)(cout + (size_t)pg*DIM + d0) = f4;
      }
    }
  }
}

// ---------------- per-cell mean of h (bf16 gather; mean-grid into gbf) ----------------
__global__ __launch_bounds__(256) void k_cellmean(const unsigned short* __restrict__ h,
    const int* __restrict__ off, const int* __restrict__ cnt,
    const int* __restrict__ list, unsigned short* __restrict__ mgrid){
  const int seg = (blockIdx.x * 256 + threadIdx.x) >> 6;   // 49152 waves
  const int l = threadIdx.x & 63;
  const int base = off[seg], n = cnt[seg];
  float s0 = 0.f, s1 = 0.f;
  int i = 0;
  for (; i + 4 <= n; i += 4){
    int p0 = list[base+i], p1 = list[base+i+1], p2 = list[base+i+2], p3 = list[base+i+3];
    unsigned int u0 = *(const unsigned int*)(h + p0*DIM + 2*l);
    unsigned int u1 = *(const unsigned int*)(h + p1*DIM + 2*l);
    unsigned int u2 = *(const unsigned int*)(h + p2*DIM + 2*l);
    unsigned int u3 = *(const unsigned int*)(h + p3*DIM + 2*l);
    s0 += (bflo(u0) + bflo(u1)) + (bflo(u2) + bflo(u3));
    s1 += (bfhi(u0) + bfhi(u1)) + (bfhi(u2) + bfhi(u3));
  }
  for (; i < n; ++i){
    int p = list[base+i];
    unsigned int u = *(const unsigned int*)(h + p*DIM + 2*l);
    s0 += bflo(u); s1 += bfhi(u);
  }
  float den = 1.0f / (float)(n < 1 ? 1 : n);
  unsigned int o = (unsigned int)f2bf(s0 * den) | ((unsigned int)f2bf(s1 * den) << 16);
  *(unsigned int*)(mgrid + (size_t)seg*DIM + 2*l) = o;
}

// ---------------- tri = mgrid @ fcW + b (empty cells -> 0), transposed write ----------------
__global__ __launch_bounds__(256) void k_trigemm(const unsigned short* __restrict__ mgrid,
    const unsigned short* __restrict__ fcf, const float* __restrict__ fcb,
    const int* __restrict__ cnt, float* __restrict__ tri)
{
  __shared__ unsigned short lh[64*128];
  const int t = threadIdx.x;
  const int wg = blockIdx.x;              // 768 = NSEG/64; 64 cells each
  const int pl = wg >> 8;
  const int b  = (wg >> 6) & 3;
  const int r  = wg & 63;
  const int segbase = (pl*B_+b)*R2 + r*64;
  {
    int dg4 = (t & 31) * 4, prow = t >> 5;
    #pragma unroll
    for (int pass = 0; pass < 8; ++pass){
      int p = prow + pass*8;
      uint2 hv = *(const uint2*)(mgrid + (size_t)(segbase + p)*DIM + dg4);
      *(uint2*)((char*)lh + p*256 + ((dg4*2) ^ ((p & 15) << 4))) = hv;
    }
  }
  __syncthreads();
  const int w = t >> 6, l = t & 63, lm = l & 31, hi = l >> 5;
  const int D0 = w*32, swz = (lm & 15) << 4;
  const unsigned short* fw = fcf + ((size_t)w*8*64 + l)*8;
  f32x16 ac0, ac1;
  #pragma unroll
  for (int i = 0; i < 16; ++i){ ac0[i] = 0.f; ac1[i] = 0.f; }
  const char* r0 = (const char*)lh + lm*256;
  const char* r1 = (const char*)lh + (32+lm)*256;
  #pragma unroll
  for (int ks = 0; ks < 8; ++ks){
    bf16x8 a = *(const bf16x8*)(fw + ks*512);
    int kb = (ks*32 + hi*16) ^ swz;
    ac0 = MFMA(a, *(const bf16x8*)(r0 + kb), ac0);
    ac1 = MFMA(a, *(const bf16x8*)(r1 + kb), ac1);
  }
  // empty-cell mask (reference: empty cell -> 0, not bias)
  float z0 = (cnt[segbase + lm]      > 0) ? 1.0f : 0.0f;
  float z1 = (cnt[segbase + 32 + lm] > 0) ? 1.0f : 0.0f;
  float* dst = tri + ((size_t)((pl*B_+b)*DIM)) * R2 + r*64;
  #pragma unroll
  for (int g = 0; g < 4; ++g){
    int d0 = D0 + 8*g + 4*hi;
    #pragma unroll
    for (int j = 0; j < 4; ++j){
      int d = d0 + j;
      float q = fcb[d];
      dst[(size_t)d*R2 + lm]      = (ac0[4*g+j] + q) * z0;
      dst[(size_t)d*R2 + 32 + lm] = (ac1[4*g+j] + q) * z1;
    }
  }
}

// ---------------- launch ----------------
extern "C" void kernel_launch(void* const* d_in, const int* in_sizes, int n_in,
                              void* d_out, int out_size, void* d_ws, size_t ws_size,
                              hipStream_t stream){
  const float* x      = (const float*)d_in[0];
  const float* stem_w = (const float*)d_in[1];
  const float* stem_b = (const float*)d_in[2];
  const float* fc0_w  = (const float*)d_in[3];
  const float* fc0_b  = (const float*)d_in[4];
  const float* fc1_w  = (const float*)d_in[5];
  const float* fc1_b  = (const float*)d_in[6];
  const float* sc_w   = (const float*)d_in[7];
  const float* sc_b   = (const float*)d_in[8];
  const float* fcc_w  = (const float*)d_in[9];
  const float* fcc_b  = (const float*)d_in[10];

  char* ws = (char*)d_ws;
  int* idx4           = (int*)(ws + O_IDX);
  int* cnt            = (int*)(ws + O_CNT);
  int* off            = (int*)(ws + O_OFF);
  int* woff           = (int*)(ws + O_WOFF);
  int* list           = (int*)(ws + O_LIST);
  unsigned short* h   = (unsigned short*)(ws + O_H);
  unsigned short* gbf = (unsigned short*)(ws + O_GRID);  // max-grid; reused as mean-grid
  unsigned short* wbf = (unsigned short*)(ws + O_W);

  float* out     = (float*)d_out;
  float* out_xyz = out;
  float* out_c   = out + OUT_C_OFF;
  float* out_tri = out + OUT_TRI_OFF;

  hipMemsetAsync(cnt, 0, NSEG*4, stream);
  k_prep<<<BN/256, 256, 0, stream>>>(x, out_xyz, idx4, cnt);
  k_prepw<<<1664, 256, 0, stream>>>(fc0_w, fc1_w, sc_w, fcc_w, wbf);
  k_scan<<<1, 1024, 0, stream>>>(cnt, off, woff);
  k_bin<<<BN/256, 256, 0, stream>>>(idx4, woff, list);

  const unsigned short* fcf = wbf + (size_t)5*WBLK_ELEMS;

  // block 0 (stem input)
  k_block<0><<<BN/64, 256, 0, stream>>>(x, stem_w, stem_b, h, nullptr, nullptr,
                                        wbf, fc0_b, fc1_b, sc_b,
                                        nullptr, nullptr, nullptr);
  // blocks 1..3 (pool + concat input)
  for (int i = 1; i < NBLK-1; ++i){
    k_cellmax<<<NSEG/4, 256, 0, stream>>>(h, off, cnt, list, gbf);
    k_block<1><<<BN/64, 256, 0, stream>>>(nullptr, nullptr, nullptr, h, gbf, idx4,
                                          wbf + (size_t)i*WBLK_ELEMS,
                                          fc0_b + i*DIM, fc1_b + i*DIM, sc_b + i*DIM,
                                          nullptr, nullptr, nullptr);
  }
  // block 4: fused with final projection (writes h AND c)
  k_cellmax<<<NSEG/4, 256, 0, stream>>>(h, off, cnt, list, gbf);
  k_block<2><<<BN/64, 256, 0, stream>>>(nullptr, nullptr, nullptr, h, gbf, idx4,
                                        wbf + (size_t)4*WBLK_ELEMS,
                                        fc0_b + 4*DIM, fc1_b + 4*DIM, sc_b + 4*DIM,
                                        fcf, fcc_b, out_c);
  // pooled-mean of h, tri projection
  k_cellmean<<<NSEG/4, 256, 0, stream>>>(h, off, cnt, list, gbf);
  k_trigemm<<<768, 256, 0, stream>>>(gbf, fcf, fcc_b, cnt, out_tri);
}

// Round 12
// 411.872 us; speedup vs baseline: 1.4811x; 1.4811x over previous
//
#include <hip/hip_runtime.h>
#include <hip/hip_bf16.h>

#define B_   4
#define NPTS 32768
#define BN   131072
#define RES  64
#define R2   4096
#define DIM  128
#define K2   256
#define NBLK 5
#define NSEG (3*B_*R2)        // 49152 segments (plane,batch,cell)

typedef __bf16 bf16x8 __attribute__((ext_vector_type(8)));
typedef float  f32x16 __attribute__((ext_vector_type(16)));
typedef unsigned int uintv4 __attribute__((ext_vector_type(4)));

#define MFMA(a,b,c) __builtin_amdgcn_mfma_f32_32x32x16_bf16((a),(b),(c),0,0,0)

// ---------------- workspace layout (bytes) ----------------
#define O_IDX  0                          // BN*16 (int4 per point)
#define O_CNT  (O_IDX + BN*16)            // NSEG*4
#define O_OFF  (O_CNT + NSEG*4)
#define O_WOFF (O_OFF + NSEG*4)
#define O_LIST (O_WOFF + NSEG*4)          // 3*BN*4
#define O_H    (O_LIST + 3*BN*4)          // BN*DIM*2
#define O_GRID (O_H + BN*DIM*2)           // NSEG*DIM*2 (bf16 max-grid; reused as mean-grid)
#define O_W    (O_GRID + NSEG*DIM*2)      // fragment-ordered bf16 weights
#define WBLK_ELEMS 81920                  // w0f(32768)+wsf(32768)+w1f(16384)

// ---------------- output layout (floats) ----------------
#define OUT_C_OFF   393216
#define OUT_TRI_OFF 17170432

// ---------------- helpers ----------------
__device__ __forceinline__ unsigned short f2bf(float f){
  unsigned int u = __float_as_uint(f);
  return (unsigned short)((u + 0x7fffu + ((u >> 16) & 1u)) >> 16);
}
__device__ __forceinline__ float bflo(unsigned int u){ return __uint_as_float(u << 16); }
__device__ __forceinline__ float bfhi(unsigned int u){ return __uint_as_float(u & 0xffff0000u); }
__device__ __forceinline__ int coord_bin(float u){
  float p = u / 1.101f + 0.5f;                 // matches f32(1.0+PAD+0.001)
  p = fminf(fmaxf(p, 0.0f), (float)(1.0 - 1e-6));
  int i = (int)(p * 64.0f);
  return i < 0 ? 0 : (i > 63 ? 63 : i);
}
__device__ __forceinline__ unsigned int pk_relu(unsigned int a){
  unsigned int r, z = 0;
  asm("v_pk_max_f16 %0, %1, %2" : "=v"(r) : "v"(a), "v"(z));
  return r;
}
__device__ __forceinline__ bf16x8 relu8(bf16x8 v){
  uintv4 u = __builtin_bit_cast(uintv4, v);
  u[0] = pk_relu(u[0]); u[1] = pk_relu(u[1]); u[2] = pk_relu(u[2]); u[3] = pk_relu(u[3]);
  return __builtin_bit_cast(bf16x8, u);
}

// ---------------- prep: indices (int4-packed), counts, xyz copy ----------------
__global__ void k_prep(const float* __restrict__ x, float* __restrict__ out_xyz,
                       int* __restrict__ idx4, int* __restrict__ cnt){
  int p = blockIdx.x * 256 + threadIdx.x;
  if (p >= BN) return;
  float x0 = x[p*3+0], x1 = x[p*3+1], x2 = x[p*3+2];
  out_xyz[p*3+0] = x0; out_xyz[p*3+1] = x1; out_xyz[p*3+2] = x2;
  int b = p >> 15;
  int c0 = coord_bin(x0) + 64*coord_bin(x2);   // plane (0,2)
  int c1 = coord_bin(x0) + 64*coord_bin(x1);   // plane (0,1)
  int c2 = coord_bin(x1) + 64*coord_bin(x2);   // plane (1,2)
  int4 c4; c4.x = c0; c4.y = c1; c4.z = c2; c4.w = 0;
  *(int4*)(idx4 + p*4) = c4;
  atomicAdd(&cnt[(0*B_+b)*R2 + c0], 1);
  atomicAdd(&cnt[(1*B_+b)*R2 + c1], 1);
  atomicAdd(&cnt[(2*B_+b)*R2 + c2], 1);
}

// ---------------- exclusive scan over NSEG counts ----------------
__global__ __launch_bounds__(1024) void k_scan(const int* __restrict__ cnt,
                                               int* __restrict__ off, int* __restrict__ woff){
  __shared__ int part[1024];
  const int t = threadIdx.x;
  const int PER = NSEG / 1024;     // 48
  const int base = t * PER;
  int s = 0;
  for (int i = 0; i < PER; ++i) s += cnt[base+i];
  part[t] = s;
  __syncthreads();
  for (int d = 1; d < 1024; d <<= 1){
    int v = (t >= d) ? part[t-d] : 0;
    __syncthreads();
    part[t] += v;
    __syncthreads();
  }
  int acc = (t == 0) ? 0 : part[t-1];
  for (int i = 0; i < PER; ++i){
    int c = cnt[base+i];
    off[base+i] = acc; woff[base+i] = acc;
    acc += c;
  }
}

// ---------------- bin points into per-cell lists ----------------
__global__ void k_bin(const int* __restrict__ idx4, int* __restrict__ woff, int* __restrict__ list){
  int p = blockIdx.x * 256 + threadIdx.x;
  if (p >= BN) return;
  int b = p >> 15;
  int4 c4 = *(const int4*)(idx4 + p*4);
  int cs[3] = {c4.x, c4.y, c4.z};
  #pragma unroll
  for (int pl = 0; pl < 3; ++pl){
    int s = (pl*B_+b)*R2 + cs[pl];
    int slot = atomicAdd(&woff[s], 1);
    list[slot] = p;
  }
}

// ---------------- prep: weights -> bf16, FRAGMENT ORDER ----------------
__global__ void k_prepw(const float* __restrict__ fc0, const float* __restrict__ fc1,
                        const float* __restrict__ scw, const float* __restrict__ fcc,
                        unsigned short* __restrict__ wdst){
  int t = blockIdx.x * 256 + threadIdx.x;
  if (t < 163840){                          // w0f per block: [4][16][64][8]  (K=256)
    int b = t >> 15, r = t & 32767;
    int j = r & 7, l = (r >> 3) & 63, ks = (r >> 9) & 15, w = r >> 13;
    int n = w*32 + (l & 31);
    int k = ks*16 + (l >> 5)*8 + j;
    wdst[b*WBLK_ELEMS + r] = f2bf(fc0[(b*256 + k)*128 + n]);
  } else if (t < 327680){                   // wsf per block
    int t2 = t - 163840;
    int b = t2 >> 15, r = t2 & 32767;
    int j = r & 7, l = (r >> 3) & 63, ks = (r >> 9) & 15, w = r >> 13;
    int n = w*32 + (l & 31);
    int k = ks*16 + (l >> 5)*8 + j;
    wdst[b*WBLK_ELEMS + 32768 + r] = f2bf(scw[(b*256 + k)*128 + n]);
  } else if (t < 409600){                   // w1f per block: [4][8][64][8]  (K=128)
    int t2 = t - 327680;
    int b = t2 >> 14, r = t2 & 16383;
    int j = r & 7, l = (r >> 3) & 63, ks = (r >> 9) & 7, w = (r >> 12) & 3;
    int n = w*32 + (l & 31);
    int k = ks*16 + (l >> 5)*8 + j;
    wdst[b*WBLK_ELEMS + 65536 + r] = f2bf(fc1[(b*128 + k)*128 + n]);
  } else if (t < 425984){                   // fcf: [4][8][64][8]
    int r = t - 409600;
    int j = r & 7, l = (r >> 3) & 63, ks = (r >> 9) & 7, w = (r >> 12) & 3;
    int n = w*32 + (l & 31);
    int k = ks*16 + (l >> 5)*8 + j;
    wdst[5*WBLK_ELEMS + r] = f2bf(fcc[k*128 + n]);
  }
}

// ---------------- per-cell max (gather-reduce, no atomics) ----------------
__global__ __launch_bounds__(256) void k_cellmax(const unsigned short* __restrict__ h,
    const int* __restrict__ off, const int* __restrict__ cnt,
    const int* __restrict__ list, unsigned short* __restrict__ gbf){
  const int seg = (blockIdx.x * 256 + threadIdx.x) >> 6;   // 49152 waves
  const int l = threadIdx.x & 63;
  const int base = off[seg], n = cnt[seg];
  float m0 = -INFINITY, m1 = -INFINITY;
  int i = 0;
  for (; i + 4 <= n; i += 4){
    int p0 = list[base+i], p1 = list[base+i+1], p2 = list[base+i+2], p3 = list[base+i+3];
    unsigned int u0 = *(const unsigned int*)(h + p0*DIM + 2*l);
    unsigned int u1 = *(const unsigned int*)(h + p1*DIM + 2*l);
    unsigned int u2 = *(const unsigned int*)(h + p2*DIM + 2*l);
    unsigned int u3 = *(const unsigned int*)(h + p3*DIM + 2*l);
    m0 = fmaxf(fmaxf(fmaxf(m0, bflo(u0)), fmaxf(bflo(u1), bflo(u2))), bflo(u3));
    m1 = fmaxf(fmaxf(fmaxf(m1, bfhi(u0)), fmaxf(bfhi(u1), bfhi(u2))), bfhi(u3));
  }
  for (; i < n; ++i){
    int p = list[base+i];
    unsigned int u = *(const unsigned int*)(h + p*DIM + 2*l);
    m0 = fmaxf(m0, bflo(u)); m1 = fmaxf(m1, bfhi(u));
  }
  unsigned int o = 0;
  if (n > 0) o = (__float_as_uint(m0) >> 16) | (__float_as_uint(m1) & 0xffff0000u);
  *(unsigned int*)(gbf + (size_t)seg*DIM + 2*l) = o;
}

// ---------------- fused residual block (64-pt tile, 32 KB LDS, 4-bit swizzle) ----------------
// MODE 0: stem input. MODE 1: concat(h,pool). MODE 2: MODE1 + fused c = h@fc + b.
template<int MODE>
__global__ __launch_bounds__(256, 4) void k_block(
    const float* __restrict__ x,
    const float* __restrict__ stem_w, const float* __restrict__ stem_b,
    unsigned short* __restrict__ h,
    const unsigned short* __restrict__ gbf, const int* __restrict__ idx4,
    const unsigned short* __restrict__ wT,
    const float* __restrict__ b0g, const float* __restrict__ b1g, const float* __restrict__ bsg,
    const unsigned short* __restrict__ fcf, const float* __restrict__ fcb,
    float* __restrict__ cout)
{
  __shared__ unsigned short lh2[64*256];   // 32768 B
  const int t = threadIdx.x;
  const int tile0 = blockIdx.x * 64;

  if (MODE == 0){
    const int dg8 = (t & 31) * 8;
    const int prow = t >> 5;
    float wa[8], wb[8], wc[8], bb[8];
    #pragma unroll
    for (int j = 0; j < 8; ++j){
      wa[j] = stem_w[dg8+j]; wb[j] = stem_w[256+dg8+j]; wc[j] = stem_w[512+dg8+j];
      bb[j] = stem_b[dg8+j];
    }
    #pragma unroll
    for (int pass = 0; pass < 8; ++pass){
      int p = prow + pass*8;
      int pg = tile0 + p;
      float x0 = x[pg*3+0], x1 = x[pg*3+1], x2 = x[pg*3+2];
      unsigned int pk[4];
      #pragma unroll
      for (int j = 0; j < 4; ++j){
        float v0 = bb[2*j]   + x0*wa[2*j]   + x1*wb[2*j]   + x2*wc[2*j];
        float v1 = bb[2*j+1] + x0*wa[2*j+1] + x1*wb[2*j+1] + x2*wc[2*j+1];
        pk[j] = (unsigned int)f2bf(v0) | ((unsigned int)f2bf(v1) << 16);
      }
      uint4 q; q.x = pk[0]; q.y = pk[1]; q.z = pk[2]; q.w = pk[3];
      *(uint4*)((char*)lh2 + p*512 + ((dg8*2) ^ ((p & 15) << 4))) = q;
    }
  } else {
    const int dg4 = (t & 31) * 4;
    const int prow = t >> 5;
    // phase 1: preload all cell indices (fully unrolled -> registers)
    int4 cl[8];
    #pragma unroll
    for (int pass = 0; pass < 8; ++pass)
      cl[pass] = *(const int4*)(idx4 + (tile0 + prow + pass*8)*4);
    // phase 2: gather + stage (fully unrolled so cl[pass] is static)
    #pragma unroll
    for (int pass = 0; pass < 8; ++pass){
      int p = prow + pass*8;
      int pg = tile0 + p;
      int b = pg >> 15;
      uint2 hv = *(const uint2*)(h + pg*DIM + dg4);
      const unsigned short* g0 = gbf + ((size_t)((0*B_+b)*R2 + cl[pass].x))*DIM + dg4;
      const unsigned short* g1 = gbf + ((size_t)((1*B_+b)*R2 + cl[pass].y))*DIM + dg4;
      const unsigned short* g2 = gbf + ((size_t)((2*B_+b)*R2 + cl[pass].z))*DIM + dg4;
      uint2 v0 = *(const uint2*)g0;
      uint2 v1 = *(const uint2*)g1;
      uint2 v2 = *(const uint2*)g2;
      *(uint2*)((char*)lh2 + p*512 + ((dg4*2) ^ ((p & 15) << 4))) = hv;
      float s0 = bflo(v0.x) + bflo(v1.x) + bflo(v2.x);
      float s1 = bfhi(v0.x) + bfhi(v1.x) + bfhi(v2.x);
      float s2 = bflo(v0.y) + bflo(v1.y) + bflo(v2.y);
      float s3 = bfhi(v0.y) + bfhi(v1.y) + bfhi(v2.y);
      uint2 pv;
      pv.x = (unsigned int)f2bf(s0) | ((unsigned int)f2bf(s1) << 16);
      pv.y = (unsigned int)f2bf(s2) | ((unsigned int)f2bf(s3) << 16);
      *(uint2*)((char*)lh2 + p*512 + (((128 + dg4)*2) ^ ((p & 15) << 4))) = pv;
    }
  }
  __syncthreads();

  // ---- GEMM phase: A = weights (fragment-ordered), B = points (LDS) ----
  const int w  = t >> 6;
  const int l  = t & 63;
  const int lm = l & 31;
  const int hi = l >> 5;
  const int D0 = w * 32;
  const int swz  = (lm & 15) << 4;
  const unsigned short* w0f = wT +          ((size_t)w*16*64 + l)*8;
  const unsigned short* wsf = wT + 32768 +  ((size_t)w*16*64 + l)*8;
  const unsigned short* w1f = wT + 65536 +  ((size_t)w* 8*64 + l)*8;

  f32x16 an0, an1, as0, as1;
  #pragma unroll
  for (int i = 0; i < 16; ++i){ an0[i] = 0.f; an1[i] = 0.f; as0[i] = 0.f; as1[i] = 0.f; }

  const char* lr0 = (const char*)lh2 + lm*512;
  const char* lr1 = (const char*)lh2 + (32+lm)*512;

  #pragma unroll 4
  for (int ks = 0; ks < 16; ++ks){
    bf16x8 a0 = *(const bf16x8*)(w0f + ks*512);
    bf16x8 a1 = *(const bf16x8*)(wsf + ks*512);
    int kb = (ks*32 + hi*16) ^ swz;
    bf16x8 br0 = *(const bf16x8*)(lr0 + kb);
    bf16x8 br1 = *(const bf16x8*)(lr1 + kb);
    an0 = MFMA(a0, relu8(br0), an0);
    as0 = MFMA(a1, br0, as0);
    an1 = MFMA(a0, relu8(br1), an1);
    as1 = MFMA(a1, br1, as1);
  }

  __syncthreads();   // all waves done reading lh2 before aliased net-write

  // net = GEMM1 + b0, relu, write bf16 to lnet (= first 16 KB of lh2)
  {
    char* nr0 = (char*)lh2 + lm*256;
    char* nr1 = (char*)lh2 + (32+lm)*256;
    #pragma unroll
    for (int g = 0; g < 4; ++g){
      int d0 = D0 + 8*g + 4*hi;
      float q0 = b0g[d0], q1 = b0g[d0+1], q2 = b0g[d0+2], q3 = b0g[d0+3];
      uint2 u0, u1;
      {
        float v0 = fmaxf(an0[4*g+0]+q0, 0.f), v1 = fmaxf(an0[4*g+1]+q1, 0.f);
        float v2 = fmaxf(an0[4*g+2]+q2, 0.f), v3 = fmaxf(an0[4*g+3]+q3, 0.f);
        u0.x = (unsigned int)f2bf(v0) | ((unsigned int)f2bf(v1) << 16);
        u0.y = (unsigned int)f2bf(v2) | ((unsigned int)f2bf(v3) << 16);
      }
      {
        float v0 = fmaxf(an1[4*g+0]+q0, 0.f), v1 = fmaxf(an1[4*g+1]+q1, 0.f);
        float v2 = fmaxf(an1[4*g+2]+q2, 0.f), v3 = fmaxf(an1[4*g+3]+q3, 0.f);
        u1.x = (unsigned int)f2bf(v0) | ((unsigned int)f2bf(v1) << 16);
        u1.y = (unsigned int)f2bf(v2) | ((unsigned int)f2bf(v3) << 16);
      }
      int ob = (d0*2) ^ swz;
      *(uint2*)(nr0 + ob) = u0;
      *(uint2*)(nr1 + ob) = u1;
    }
  }
  __syncthreads();

  // dx = relu(net) @ w1
  f32x16 ad0, ad1;
  #pragma unroll
  for (int i = 0; i < 16; ++i){ ad0[i] = 0.f; ad1[i] = 0.f; }
  const char* nr0c = (const char*)lh2 + lm*256;
  const char* nr1c = (const char*)lh2 + (32+lm)*256;
  #pragma unroll 4
  for (int ks = 0; ks < 8; ++ks){
    bf16x8 a = *(const bf16x8*)(w1f + ks*512);
    int kb = (ks*32 + hi*16) ^ swz;
    ad0 = MFMA(a, *(const bf16x8*)(nr0c + kb), ad0);
    ad1 = MFMA(a, *(const bf16x8*)(nr1c + kb), ad1);
  }

  // h_next = sc + bs + dx + b1 ; keep packed values for MODE2 fusion
  uint2 oa[4], ob_[4];
  #pragma unroll
  for (int g = 0; g < 4; ++g){
    int d0 = D0 + 8*g + 4*hi;
    float p0 = b1g[d0]   + bsg[d0];
    float p1 = b1g[d0+1] + bsg[d0+1];
    float p2 = b1g[d0+2] + bsg[d0+2];
    float p3 = b1g[d0+3] + bsg[d0+3];
    {
      float v0 = as0[4*g+0]+ad0[4*g+0]+p0, v1 = as0[4*g+1]+ad0[4*g+1]+p1;
      float v2 = as0[4*g+2]+ad0[4*g+2]+p2, v3 = as0[4*g+3]+ad0[4*g+3]+p3;
      oa[g].x = (unsigned int)f2bf(v0) | ((unsigned int)f2bf(v1) << 16);
      oa[g].y = (unsigned int)f2bf(v2) | ((unsigned int)f2bf(v3) << 16);
      *(uint2*)(h + (tile0 + lm)*DIM + d0) = oa[g];
    }
    {
      float v0 = as1[4*g+0]+ad1[4*g+0]+p0, v1 = as1[4*g+1]+ad1[4*g+1]+p1;
      float v2 = as1[4*g+2]+ad1[4*g+2]+p2, v3 = as1[4*g+3]+ad1[4*g+3]+p3;
      ob_[g].x = (unsigned int)f2bf(v0) | ((unsigned int)f2bf(v1) << 16);
      ob_[g].y = (unsigned int)f2bf(v2) | ((unsigned int)f2bf(v3) << 16);
      *(uint2*)(h + (tile0 + 32 + lm)*DIM + d0) = ob_[g];
    }
  }

  if (MODE == 2){
    // ---- fused final projection: c = h@fc + b, h-tile staged via lh2 ----
    __syncthreads();   // all waves done reading lnet before overwrite
    {
      char* hr0 = (char*)lh2 + lm*256;
      char* hr1 = (char*)lh2 + (32+lm)*256;
      #pragma unroll
      for (int g = 0; g < 4; ++g){
        int d0 = D0 + 8*g + 4*hi;
        int ob = (d0*2) ^ swz;
        *(uint2*)(hr0 + ob) = oa[g];
        *(uint2*)(hr1 + ob) = ob_[g];
      }
    }
    __syncthreads();
    const unsigned short* fw = fcf + ((size_t)w*8*64 + l)*8;
    f32x16 ac0, ac1;
    #pragma unroll
    for (int i = 0; i < 16; ++i){ ac0[i] = 0.f; ac1[i] = 0.f; }
    #pragma unroll 4
    for (int ks = 0; ks < 8; ++ks){
      bf16x8 a = *(const bf16x8*)(fw + ks*512);
      int kb = (ks*32 + hi*16) ^ swz;
      ac0 = MFMA(a, *(const bf16x8*)(nr0c + kb), ac0);
      ac1 = MFMA(a, *(const bf16x8*)(nr1c + kb), ac1);
    }
    #pragma unroll
    for (int g = 0; g < 4; ++g){
      int d0 = D0 + 8*g + 4*hi;
      float q0 = fcb[d0], q1 = fcb[d0+1], q2 = fcb[d0+2], q3 = fcb[d0+3];
      {
        int pg = tile0 + lm;
        float4 f4;
        f4.x = ac0[4*g+0]+q0; f4.y = ac0[4*g+1]+q1; f4.z = ac0[4*g+2]+q2; f4.w = ac0[4*g+3]+q3;
        *(float4*)(cout + (size_t)pg*DIM + d0) = f4;
      }
      {
        int pg = tile0 + 32 + lm;
        float4 f4;
        f4.x = ac1[4*g+0]+q0; f4.y = ac1[4*g+1]+q1; f4.z = ac1[4*g+2]+q2; f4.w = ac1[4*g+3]+q3;
        *(float4*)(cout + (size_t)pg*DIM + d0) = f4;
      }
    }
  }
}

// ---------------- per-cell mean of h (bf16 gather; mean-grid into gbf) ----------------
__global__ __launch_bounds__(256) void k_cellmean(const unsigned short* __restrict__ h,
    const int* __restrict__ off, const int* __restrict__ cnt,
    const int* __restrict__ list, unsigned short* __restrict__ mgrid){
  const int seg = (blockIdx.x * 256 + threadIdx.x) >> 6;   // 49152 waves
  const int l = threadIdx.x & 63;
  const int base = off[seg], n = cnt[seg];
  float s0 = 0.f, s1 = 0.f;
  int i = 0;
  for (; i + 4 <= n; i += 4){
    int p0 = list[base+i], p1 = list[base+i+1], p2 = list[base+i+2], p3 = list[base+i+3];
    unsigned int u0 = *(const unsigned int*)(h + p0*DIM + 2*l);
    unsigned int u1 = *(const unsigned int*)(h + p1*DIM + 2*l);
    unsigned int u2 = *(const unsigned int*)(h + p2*DIM + 2*l);
    unsigned int u3 = *(const unsigned int*)(h + p3*DIM + 2*l);
    s0 += (bflo(u0) + bflo(u1)) + (bflo(u2) + bflo(u3));
    s1 += (bfhi(u0) + bfhi(u1)) + (bfhi(u2) + bfhi(u3));
  }
  for (; i < n; ++i){
    int p = list[base+i];
    unsigned int u = *(const unsigned int*)(h + p*DIM + 2*l);
    s0 += bflo(u); s1 += bfhi(u);
  }
  float den = 1.0f / (float)(n < 1 ? 1 : n);
  unsigned int o = (unsigned int)f2bf(s0 * den) | ((unsigned int)f2bf(s1 * den) << 16);
  *(unsigned int*)(mgrid + (size_t)seg*DIM + 2*l) = o;
}

// ---------------- tri = mgrid @ fcW + b (empty cells -> 0), transposed write ----------------
__global__ __launch_bounds__(256) void k_trigemm(const unsigned short* __restrict__ mgrid,
    const unsigned short* __restrict__ fcf, const float* __restrict__ fcb,
    const int* __restrict__ cnt, float* __restrict__ tri)
{
  __shared__ unsigned short lh[64*128];
  const int t = threadIdx.x;
  const int wg = blockIdx.x;              // 768 = NSEG/64; 64 cells each
  const int pl = wg >> 8;
  const int b  = (wg >> 6) & 3;
  const int r  = wg & 63;
  const int segbase = (pl*B_+b)*R2 + r*64;
  {
    int dg4 = (t & 31) * 4, prow = t >> 5;
    #pragma unroll
    for (int pass = 0; pass < 8; ++pass){
      int p = prow + pass*8;
      uint2 hv = *(const uint2*)(mgrid + (size_t)(segbase + p)*DIM + dg4);
      *(uint2*)((char*)lh + p*256 + ((dg4*2) ^ ((p & 15) << 4))) = hv;
    }
  }
  __syncthreads();
  const int w = t >> 6, l = t & 63, lm = l & 31, hi = l >> 5;
  const int D0 = w*32, swz = (lm & 15) << 4;
  const unsigned short* fw = fcf + ((size_t)w*8*64 + l)*8;
  f32x16 ac0, ac1;
  #pragma unroll
  for (int i = 0; i < 16; ++i){ ac0[i] = 0.f; ac1[i] = 0.f; }
  const char* r0 = (const char*)lh + lm*256;
  const char* r1 = (const char*)lh + (32+lm)*256;
  #pragma unroll 4
  for (int ks = 0; ks < 8; ++ks){
    bf16x8 a = *(const bf16x8*)(fw + ks*512);
    int kb = (ks*32 + hi*16) ^ swz;
    ac0 = MFMA(a, *(const bf16x8*)(r0 + kb), ac0);
    ac1 = MFMA(a, *(const bf16x8*)(r1 + kb), ac1);
  }
  // empty-cell mask (reference: empty cell -> 0, not bias)
  float z0 = (cnt[segbase + lm]      > 0) ? 1.0f : 0.0f;
  float z1 = (cnt[segbase + 32 + lm] > 0) ? 1.0f : 0.0f;
  float* dst = tri + ((size_t)((pl*B_+b)*DIM)) * R2 + r*64;
  #pragma unroll
  for (int g = 0; g < 4; ++g){
    int d0 = D0 + 8*g + 4*hi;
    #pragma unroll
    for (int j = 0; j < 4; ++j){
      int d = d0 + j;
      float q = fcb[d];
      dst[(size_t)d*R2 + lm]      = (ac0[4*g+j] + q) * z0;
      dst[(size_t)d*R2 + 32 + lm] = (ac1[4*g+j] + q) * z1;
    }
  }
}

// ---------------- launch ----------------
extern "C" void kernel_launch(void* const* d_in, const int* in_sizes, int n_in,
                              void* d_out, int out_size, void* d_ws, size_t ws_size,
                              hipStream_t stream){
  const float* x      = (const float*)d_in[0];
  const float* stem_w = (const float*)d_in[1];
  const float* stem_b = (const float*)d_in[2];
  const float* fc0_w  = (const float*)d_in[3];
  const float* fc0_b  = (const float*)d_in[4];
  const float* fc1_w  = (const float*)d_in[5];
  const float* fc1_b  = (const float*)d_in[6];
  const float* sc_w   = (const float*)d_in[7];
  const float* sc_b   = (const float*)d_in[8];
  const float* fcc_w  = (const float*)d_in[9];
  const float* fcc_b  = (const float*)d_in[10];

  char* ws = (char*)d_ws;
  int* idx4           = (int*)(ws + O_IDX);
  int* cnt            = (int*)(ws + O_CNT);
  int* off            = (int*)(ws + O_OFF);
  int* woff           = (int*)(ws + O_WOFF);
  int* list           = (int*)(ws + O_LIST);
  unsigned short* h   = (unsigned short*)(ws + O_H);
  unsigned short* gbf = (unsigned short*)(ws + O_GRID);  // max-grid; reused as mean-grid
  unsigned short* wbf = (unsigned short*)(ws + O_W);

  float* out     = (float*)d_out;
  float* out_xyz = out;
  float* out_c   = out + OUT_C_OFF;
  float* out_tri = out + OUT_TRI_OFF;

  hipMemsetAsync(cnt, 0, NSEG*4, stream);
  k_prep<<<BN/256, 256, 0, stream>>>(x, out_xyz, idx4, cnt);
  k_prepw<<<1664, 256, 0, stream>>>(fc0_w, fc1_w, sc_w, fcc_w, wbf);
  k_scan<<<1, 1024, 0, stream>>>(cnt, off, woff);
  k_bin<<<BN/256, 256, 0, stream>>>(idx4, woff, list);

  const unsigned short* fcf = wbf + (size_t)5*WBLK_ELEMS;

  // block 0 (stem input)
  k_block<0><<<BN/64, 256, 0, stream>>>(x, stem_w, stem_b, h, nullptr, nullptr,
                                        wbf, fc0_b, fc1_b, sc_b,
                                        nullptr, nullptr, nullptr);
  // blocks 1..3 (pool + concat input)
  for (int i = 1; i < NBLK-1; ++i){
    k_cellmax<<<NSEG/4, 256, 0, stream>>>(h, off, cnt, list, gbf);
    k_block<1><<<BN/64, 256, 0, stream>>>(nullptr, nullptr, nullptr, h, gbf, idx4,
                                          wbf + (size_t)i*WBLK_ELEMS,
                                          fc0_b + i*DIM, fc1_b + i*DIM, sc_b + i*DIM,
                                          nullptr, nullptr, nullptr);
  }
  // block 4: fused with final projection (writes h AND c)
  k_cellmax<<<NSEG/4, 256, 0, stream>>>(h, off, cnt, list, gbf);
  k_block<2><<<BN/64, 256, 0, stream>>>(nullptr, nullptr, nullptr, h, gbf, idx4,
                                        wbf + (size_t)4*WBLK_ELEMS,
                                        fc0_b + 4*DIM, fc1_b + 4*DIM, sc_b + 4*DIM,
                                        fcf, fcc_b, out_c);
  // pooled-mean of h, tri projection
  k_cellmean<<<NSEG/4, 256, 0, stream>>>(h, off, cnt, list, gbf);
  k_trigemm<<<768, 256, 0, stream>>>(gbf, fcf, fcc_b, cnt, out_tri);
}